// Round 21
// baseline (722.962 us; speedup 1.0000x reference)
//
#include <hip/hip_runtime.h>
#include <math.h>

#define BATCH 4
#define DLAT 16
#define KCB 8192
#define HLAT 122
#define PIX (HLAT*HLAT)          // 14884
#define NLAT (BATCH*PIX)         // 59536
#define NT32 (KCB/32)            // 256 codeword tiles (32 cols each)
#define ROWSB 32                 // rows per vq block
#define NVQBLK 1861              // ceil(59536/32)
#define NWAVE 4                  // waves per vq block
#define TW (NT32/NWAVE)          // 64 tiles per wave
#define SEED 8                   // seed tiles (256 codewords) per wave
#define CAPW 2048                // candidate list capacity per block
#define NCONVBLK 3721            // conv3_last blocks (= 952576/256)

typedef _Float16 half8 __attribute__((ext_vector_type(8)));
typedef float f32x16 __attribute__((ext_vector_type(16)));

// jax.nn.selu in fp32: scale * where(x>0, x, alpha*expm1(x))
__device__ __forceinline__ float selu_np(float x) {
    const float scale = 1.0507009873554805f, alpha = 1.6732632423543772f;
    if (x > 0.f) return __fmul_rn(scale, x);
    return __fmul_rn(scale, __fmul_rn(alpha, expm1f(x)));
}

// ---- fp32 VALID 3x3 conv, NCHW/OIHW, np-order: acc=0; fma over (c,p,q); +bias after ----
template<int CI, int CO, int HIN, int WIN, bool DOSELU>
__global__ void conv3x3_np(const float* __restrict__ in, const float* __restrict__ w,
                           const float* __restrict__ bias, float* __restrict__ out) {
    constexpr int HO = HIN - 2, WO = WIN - 2;
    int tid = blockIdx.x * blockDim.x + threadIdx.x;
    constexpr int total = BATCH * CO * HO * WO;
    if (tid >= total) return;
    int j = tid % WO; int t = tid / WO;
    int i = t % HO;   t /= HO;
    int o = t % CO;   int b = t / CO;
    float acc = 0.f;
    for (int c = 0; c < CI; ++c) {
        const float* ip = in + ((b * CI + c) * HIN + i) * WIN + j;
        const float* wp = w + ((o * CI + c) * 3) * 3;
        #pragma unroll
        for (int p = 0; p < 3; ++p)
            #pragma unroll
            for (int q = 0; q < 3; ++q)
                acc = __fmaf_rn(ip[p * WIN + q], wp[p * 3 + q], acc);
    }
    acc = __fadd_rn(acc, bias[o]);
    out[tid] = DOSELU ? selu_np(acc) : acc;
}

// ---- last encoder conv, o-fastest mapping: coalesced zf/zh, block-local max ----
__global__ void conv3_last_np(const float* __restrict__ in, const float* __restrict__ w,
                              const float* __restrict__ bias, float* __restrict__ zf,
                              _Float16* __restrict__ zh, float* __restrict__ blockmax) {
    constexpr int CI = 8, HIN = 124, WIN = 124, WO = 122;
    __shared__ float sred[4];
    int tid = blockIdx.x * 256 + threadIdx.x;   // 3721*256 = 952576 exact
    int o  = tid & 15;
    int pp = tid >> 4;                          // latent row 0..59535
    int b = pp / PIX, pix = pp % PIX;
    int i = pix / WO, j = pix % WO;
    float acc = 0.f;
    for (int c = 0; c < CI; ++c) {
        const float* ip = in + ((b * CI + c) * HIN + i) * WIN + j;
        const float* wp = w + ((o * CI + c) * 3) * 3;
        #pragma unroll
        for (int p = 0; p < 3; ++p)
            #pragma unroll
            for (int q = 0; q < 3; ++q)
                acc = __fmaf_rn(ip[p * WIN + q], wp[p * 3 + q], acc);
    }
    acc = __fadd_rn(acc, bias[o]);
    zf[tid] = acc;                 // = zf[pp*16+o], coalesced
    zh[tid] = (_Float16)acc;
    float m = fabsf(acc);
    #pragma unroll
    for (int off = 32; off; off >>= 1) m = fmaxf(m, __shfl_xor(m, off));
    if ((threadIdx.x & 63) == 0) sred[threadIdx.x >> 6] = m;
    __syncthreads();
    if (threadIdx.x == 0)
        blockmax[blockIdx.x] = fmaxf(fmaxf(sred[0], sred[1]), fmaxf(sred[2], sred[3]));
}

// ---- reduce blockmax -> scal[0]; also init scal[1]=0 (runs before cbprep) ----
__global__ void reduce_zmax(const float* __restrict__ bm, unsigned* __restrict__ scal) {
    __shared__ float sred[4];
    float m = 0.f;
    for (int i = threadIdx.x; i < NCONVBLK; i += 256) m = fmaxf(m, bm[i]);
    #pragma unroll
    for (int off = 32; off; off >>= 1) m = fmaxf(m, __shfl_xor(m, off));
    if ((threadIdx.x & 63) == 0) sred[threadIdx.x >> 6] = m;
    __syncthreads();
    if (threadIdx.x == 0)
        scal[0] = __float_as_uint(fmaxf(fmaxf(sred[0], sred[1]), fmaxf(sred[2], sred[3])));
    if (threadIdx.x == 1) scal[1] = 0u;
}

// ---- numpy pairwise-16 sum of squares ----
__device__ __forceinline__ float pairwise16_sq(const float* v) {
    float a[16];
    #pragma unroll
    for (int d = 0; d < 16; ++d) a[d] = __fmul_rn(v[d], v[d]);
    float r0 = __fadd_rn(a[0], a[8]),  r1 = __fadd_rn(a[1], a[9]);
    float r2 = __fadd_rn(a[2], a[10]), r3 = __fadd_rn(a[3], a[11]);
    float r4 = __fadd_rn(a[4], a[12]), r5 = __fadd_rn(a[5], a[13]);
    float r6 = __fadd_rn(a[6], a[14]), r7 = __fadd_rn(a[7], a[15]);
    return __fadd_rn(__fadd_rn(__fadd_rn(r0, r1), __fadd_rn(r2, r3)),
                     __fadd_rn(__fadd_rn(r4, r5), __fadd_rn(r6, r7)));
}

__device__ __forceinline__ void load16(const float* __restrict__ p, float* v) {
    const float4* r = (const float4*)p;
    float4 v0 = r[0], v1 = r[1], v2 = r[2], v3 = r[3];
    v[0]=v0.x; v[1]=v0.y; v[2]=v0.z; v[3]=v0.w;
    v[4]=v1.x; v[5]=v1.y; v[6]=v1.z; v[7]=v1.w;
    v[8]=v2.x; v[9]=v2.y; v[10]=v2.z; v[11]=v2.w;
    v[12]=v3.x; v[13]=v3.y; v[14]=v3.z; v[15]=v3.w;
}

__device__ __forceinline__ float np_d2(const float* zr, float A, const float* e16, float cnk) {
    float g = 0.f;
    #pragma unroll
    for (int d = 0; d < 16; ++d) g = __fmaf_rn(zr[d], e16[d], g);
    return __fadd_rn(__fmaf_rn(-2.f, g, A), cnk);
}

// ---- codebook prep: cn, cnT transposed [col][tile], max||e||^2, B-frag ----
__global__ void cbprep(const float* __restrict__ cb, float* __restrict__ cn,
                       float* __restrict__ cnT,
                       _Float16* __restrict__ cbB, unsigned* __restrict__ scal) {
    int k = blockIdx.x * 256 + threadIdx.x;   // 32 x 256 = 8192
    float v[16];
    load16(cb + (size_t)k * DLAT, v);
    float C = pairwise16_sq(v);
    cn[k] = C;
    int tile = k >> 5, col = k & 31;
    cnT[col * NT32 + tile] = C;
    float m = C;
    #pragma unroll
    for (int off = 32; off; off >>= 1) m = fmaxf(m, __shfl_xor(m, off));
    if ((threadIdx.x & 63) == 0) atomicMax(&scal[1], __float_as_uint(m));
    #pragma unroll
    for (int d = 0; d < 16; ++d) {
        int ln = (d >> 3) * 32 + col;          // lane 0..63
        cbB[(size_t)tile * 512 + ln * 8 + (d & 7)] = (_Float16)v[d];
    }
}

// D-reg -> row-in-group for mfma_f32_32x32x16 (col = lane&31)
#define DROW(reg, lanehi) (((reg) & 3) + 8 * ((reg) >> 2) + 4 * (lanehi))

// ---- VQ: single-pass MFMA screen (seeded running thresholds) + exact rescore ----
__global__ __launch_bounds__(256, 4) void vq_mfma(
        const _Float16* __restrict__ zh, const float* __restrict__ zf,
        const _Float16* __restrict__ cbB, const float* __restrict__ cn,
        const float* __restrict__ cnT,
        const float* __restrict__ cb, const unsigned* __restrict__ scal,
        float* __restrict__ idx_out, float* __restrict__ zq) {
    __shared__ unsigned list[CAPW];
    __shared__ float resd[CAPW];
    __shared__ float smin[NWAVE][ROWSB];
    __shared__ unsigned lcnt;
    const int tid = threadIdx.x;
    const int w = tid >> 6, lane = tid & 63;
    const int lanehi = lane >> 5;
    const int col = lane & 31;
    const int R0 = blockIdx.x * ROWSB;
    const f32x16 zero16 = {0.f,0.f,0.f,0.f,0.f,0.f,0.f,0.f,0.f,0.f,0.f,0.f,0.f,0.f,0.f,0.f};
    if (tid == 0) lcnt = 0;

    // A-frag: row = R0 + col, k = lanehi*8 + i
    int ar = R0 + col;
    if (ar >= NLAT) ar = NLAT - 1;
    half8 a = *(const half8*)(zh + (size_t)ar * DLAT + lanehi * 8);

    // rigorous screening threshold (HW-validated R7/R8)
    float zmaxf = __uint_as_float(scal[0]);
    float en    = sqrtf(__uint_as_float(scal[1]));
    float errG  = 4.f * zmaxf * en * 9.765625e-4f * 1.03f
                + 6.104e-5f * (16.f * zmaxf + 4.f * en);
    float slack = (16.f * zmaxf * zmaxf + 8.f * zmaxf * en + en * en) * 1.2e-7f;
    float DELTA = 4.f * errG + 2.f * slack + 1e-6f;

    const int t0 = w * TW, t1 = t0 + TW;
    const float* cnTl = cnT + (size_t)col * NT32;

    float known[16];
    #pragma unroll
    for (int r = 0; r < 16; ++r) known[r] = INFINITY;

    // ---- seed sweep: first SEED tiles, running min only ----
    for (int t = t0; t < t0 + SEED; t += 4) {
        float4 cn4 = *(const float4*)(cnTl + t);
        #pragma unroll
        for (int u = 0; u < 4; ++u) {
            half8 b = *(const half8*)(cbB + (size_t)(t + u) * 512 + lane * 8);
            float cnv = ((const float*)&cn4)[u];
            f32x16 D = __builtin_amdgcn_mfma_f32_32x32x16_f16(a, b, zero16, 0, 0, 0);
            #pragma unroll
            for (int r = 0; r < 16; ++r)
                known[r] = fminf(known[r], __fmaf_rn(-2.f, D[r], cnv));
        }
    }
    // cross-lane tighten (min over the 32 cols sharing lanehi)
    #pragma unroll
    for (int r = 0; r < 16; ++r) {
        float v = known[r];
        v = fminf(v, __shfl_xor(v, 1));
        v = fminf(v, __shfl_xor(v, 2));
        v = fminf(v, __shfl_xor(v, 4));
        v = fminf(v, __shfl_xor(v, 8));
        v = fminf(v, __shfl_xor(v, 16));
        known[r] = v;
    }

    // ---- main sweep: all tiles, append s <= running_min + DELTA (post-update) ----
    for (int t = t0; t < t1; t += 4) {
        float4 cn4 = *(const float4*)(cnTl + t);
        #pragma unroll
        for (int u = 0; u < 4; ++u) {
            half8 b = *(const half8*)(cbB + (size_t)(t + u) * 512 + lane * 8);
            float cnv = ((const float*)&cn4)[u];
            f32x16 D = __builtin_amdgcn_mfma_f32_32x32x16_f16(a, b, zero16, 0, 0, 0);
            float sv[16];
            bool anyp = false;
            #pragma unroll
            for (int r = 0; r < 16; ++r) {
                sv[r] = __fmaf_rn(-2.f, D[r], cnv);
                known[r] = fminf(known[r], sv[r]);
                anyp |= (sv[r] <= known[r] + DELTA);
            }
            if (__ballot(anyp)) {
                #pragma unroll
                for (int r = 0; r < 16; ++r) {
                    bool pred = (sv[r] <= known[r] + DELTA);
                    unsigned long long bal = __ballot(pred);
                    if (bal) {
                        unsigned nb = (unsigned)__popcll(bal);
                        unsigned base = 0;
                        if (lane == 0) base = atomicAdd(&lcnt, nb);
                        base = __shfl(base, 0);
                        unsigned pos = base + (unsigned)__popcll(bal & ((1ull << lane) - 1ull));
                        if (pred && pos < CAPW) {
                            unsigned rs = (unsigned)DROW(r, lanehi);
                            list[pos] = (rs << 13) | (unsigned)((t + u) * 32 + col);
                        }
                    }
                }
            }
        }
    }
    __syncthreads();
    unsigned cnt = lcnt;

    // ---- overflow fallback: exact thresholds + tight re-sweep (bounded, R13-style) ----
    if (cnt > CAPW) {
        // known now holds each lane's full observations; reduce to exact global minima
        float thr[16];
        #pragma unroll
        for (int r = 0; r < 16; ++r) {
            float v = known[r];
            v = fminf(v, __shfl_xor(v, 1));
            v = fminf(v, __shfl_xor(v, 2));
            v = fminf(v, __shfl_xor(v, 4));
            v = fminf(v, __shfl_xor(v, 8));
            v = fminf(v, __shfl_xor(v, 16));
            thr[r] = v;
        }
        if (col == 0) {
            #pragma unroll
            for (int r = 0; r < 16; ++r) smin[w][DROW(r, lanehi)] = thr[r];
        }
        __syncthreads();
        #pragma unroll
        for (int r = 0; r < 16; ++r) {
            int row = DROW(r, lanehi);
            float v = INFINITY;
            #pragma unroll
            for (int ww = 0; ww < NWAVE; ++ww) v = fminf(v, smin[ww][row]);
            thr[r] = v + DELTA;
        }
        if (tid == 0) lcnt = 0;
        __syncthreads();
        for (int t = t0; t < t1; t += 4) {
            float4 cn4 = *(const float4*)(cnTl + t);
            #pragma unroll
            for (int u = 0; u < 4; ++u) {
                half8 b = *(const half8*)(cbB + (size_t)(t + u) * 512 + lane * 8);
                float cnv = ((const float*)&cn4)[u];
                f32x16 D = __builtin_amdgcn_mfma_f32_32x32x16_f16(a, b, zero16, 0, 0, 0);
                bool anyp = false;
                float sv[16];
                #pragma unroll
                for (int r = 0; r < 16; ++r) {
                    sv[r] = __fmaf_rn(-2.f, D[r], cnv);
                    anyp |= (sv[r] <= thr[r]);
                }
                if (__ballot(anyp)) {
                    #pragma unroll
                    for (int r = 0; r < 16; ++r) {
                        bool pred = (sv[r] <= thr[r]);
                        unsigned long long bal = __ballot(pred);
                        if (bal) {
                            unsigned nb = (unsigned)__popcll(bal);
                            unsigned base = 0;
                            if (lane == 0) base = atomicAdd(&lcnt, nb);
                            base = __shfl(base, 0);
                            unsigned pos = base + (unsigned)__popcll(bal & ((1ull << lane) - 1ull));
                            if (pred && pos < CAPW) {
                                unsigned rs = (unsigned)DROW(r, lanehi);
                                list[pos] = (rs << 13) | (unsigned)((t + u) * 32 + col);
                            }
                        }
                    }
                }
            }
        }
        __syncthreads();
        cnt = lcnt;
    }

    // ---- exact np-fp32 rescore (all 256 threads) ----
    if (cnt <= CAPW) {
        for (unsigned i = tid; i < cnt; i += 256) {
            unsigned e = list[i];
            int n = R0 + (int)(e >> 13);
            if (n >= NLAT) n = NLAT - 1;
            int k = (int)(e & 8191);
            float zr[16], e16[16];
            load16(zf + (size_t)n * DLAT, zr);
            float A = pairwise16_sq(zr);
            load16(cb + (size_t)k * DLAT, e16);
            resd[i] = np_d2(zr, A, e16, cn[k]);
        }
    }
    __syncthreads();

    // ---- selection: tid = row-in-block (first-occurrence tie on k) ----
    if (tid < ROWSB) {
        int r = R0 + tid;
        if (r < NLAT) {
            float bd = INFINITY; int bk = 0x7fffffff;
            if (cnt <= CAPW) {
                for (unsigned i = 0; i < cnt; ++i) {
                    unsigned e = list[i];
                    if ((int)(e >> 13) == tid) {
                        float d2 = resd[i]; int k = (int)(e & 8191);
                        if (d2 < bd || (d2 == bd && k < bk)) { bd = d2; bk = k; }
                    }
                }
            } else {
                // absolute-safety fallback: exact per-lane full scan
                float zr[16];
                load16(zf + (size_t)r * DLAT, zr);
                float A = pairwise16_sq(zr);
                for (int k = 0; k < KCB; ++k) {
                    float e16[16];
                    load16(cb + (size_t)k * DLAT, e16);
                    float d2 = np_d2(zr, A, e16, cn[k]);
                    if (d2 < bd) { bd = d2; bk = k; }
                }
            }
            idx_out[r] = (float)bk;
            int b = r / PIX, pix = r % PIX;
            const float* e = cb + (size_t)bk * DLAT;
            #pragma unroll
            for (int d = 0; d < DLAT; ++d) zq[((size_t)(b * DLAT + d)) * PIX + pix] = e[d];
        }
    }
}

// ---- fp32 transpose conv (stride1, k3, pad2), weights (CI,CO,3,3), interior fast path ----
template<int CI, int CO, int HIN, int WIN, bool DOSELU>
__global__ void convt3x3(const float* __restrict__ in, const float* __restrict__ w,
                         const float* __restrict__ bias, float* __restrict__ out) {
    constexpr int HO = HIN + 2, WO = WIN + 2;
    int tid = blockIdx.x * blockDim.x + threadIdx.x;
    constexpr int total = BATCH * CO * HO * WO;
    if (tid >= total) return;
    int j = tid % WO; int t = tid / WO;
    int i = t % HO;   t /= HO;
    int o = t % CO;   int b = t / CO;
    float acc = bias[o];
    if (i >= 2 && i < HIN && j >= 2 && j < WIN) {
        // interior: all 9 taps in-bounds
        const float* ip0 = in + (((size_t)b * CI) * HIN + (i - 2)) * WIN + (j - 2);
        for (int c = 0; c < CI; ++c) {
            const float* ip = ip0 + (size_t)c * HIN * WIN;
            const float* wp = w + ((c * CO + o) * 3) * 3;
            #pragma unroll
            for (int p = 0; p < 3; ++p)
                #pragma unroll
                for (int q = 0; q < 3; ++q)
                    acc += ip[p * WIN + q] * wp[(2 - p) * 3 + (2 - q)];
        }
    } else {
        for (int c = 0; c < CI; ++c) {
            const float* ip = in + ((b * CI + c) * HIN) * WIN;
            const float* wp = w + ((c * CO + o) * 3) * 3;
            #pragma unroll
            for (int p = 0; p < 3; ++p) {
                int ii = i + p - 2;
                if (ii < 0 || ii >= HIN) continue;
                #pragma unroll
                for (int q = 0; q < 3; ++q) {
                    int jj = j + q - 2;
                    if (jj < 0 || jj >= WIN) continue;
                    acc += ip[ii * WIN + jj] * wp[(2 - p) * 3 + (2 - q)];
                }
            }
        }
    }
    const float scale = 1.0507009873554805f, alpha = 1.6732632423543772f;
    out[tid] = DOSELU ? (acc > 0.f ? scale * acc : scale * alpha * (expf(acc) - 1.f)) : acc;
}

extern "C" void kernel_launch(void* const* d_in, const int* in_sizes, int n_in,
                              void* d_out, int out_size, void* d_ws, size_t ws_size,
                              hipStream_t stream) {
    const float* x   = (const float*)d_in[0];
    const float* ew1 = (const float*)d_in[1];  const float* eb1 = (const float*)d_in[2];
    const float* ew2 = (const float*)d_in[3];  const float* eb2 = (const float*)d_in[4];
    const float* ew3 = (const float*)d_in[5];  const float* eb3 = (const float*)d_in[6];
    const float* dw1 = (const float*)d_in[7];  const float* db1 = (const float*)d_in[8];
    const float* dw2 = (const float*)d_in[9];  const float* db2 = (const float*)d_in[10];
    const float* dw3 = (const float*)d_in[11]; const float* db3 = (const float*)d_in[12];
    const float* cb  = (const float*)d_in[13];

    float* out_y   = (float*)d_out;                 // 196608
    float* out_idx = (float*)d_out + 196608;        // 59536 (as float)

    // ---- workspace (float offsets); ~12.3 MiB ----
    float*     ws   = (float*)d_ws;
    float*     zf   = ws;                         // [0 .. 952576)
    float*     e1   = ws + 952576;                // 254016
    float*     e2   = ws + 1206592;               // 492032 (ends 1698624)
    float*     fZq  = ws + 952576;                // decoder phase (ends 1905152)
    float*     fB   = ws + 1905152;               // 492032 (ends 2397184)
    float*     fA   = ws + 2397184;               // 254016 (ends 2651200)
    _Float16*  zh   = (_Float16*)(ws + 2651200);  // 952576 halves
    _Float16*  cbB  = (_Float16*)(ws + 3127488);  // 131072 halves
    float*     cn   = ws + 3193024;               // 8192
    float*     cnT  = ws + 3201216;               // 8192 ([col][tile])
    unsigned*  scal = (unsigned*)(ws + 3209408);  // 2
    float*     bmax = ws + 3209410;               // 3721

    const int TPB = 256;

    // encoder (fp32, np-order replica)
    conv3x3_np<3, 4, 128, 128, true ><<<993,  TPB, 0, stream>>>(x,  ew1, eb1, e1);
    conv3x3_np<4, 8, 126, 126, true ><<<1922, TPB, 0, stream>>>(e1, ew2, eb2, e2);
    conv3_last_np<<<NCONVBLK, TPB, 0, stream>>>(e2, ew3, eb3, zf, zh, bmax);
    reduce_zmax<<<1, TPB, 0, stream>>>(bmax, scal);   // also inits scal[1]

    // codebook prep + VQ (single-pass seeded screen + exact rescore)
    cbprep<<<32, TPB, 0, stream>>>(cb, cn, cnT, cbB, scal);
    vq_mfma<<<NVQBLK, TPB, 0, stream>>>(zh, zf, cbB, cn, cnT, cb, scal, out_idx, fZq);

    // decoder (fp32)
    convt3x3<16, 8, 122, 122, true ><<<1922, TPB, 0, stream>>>(fZq, dw1, db1, fB);
    convt3x3<8, 4, 124, 124, true ><<<993,  TPB, 0, stream>>>(fB,  dw2, db2, fA);
    convt3x3<4, 3, 126, 126, false><<<768,  TPB, 0, stream>>>(fA,  dw3, db3, out_y);
}

// Round 22
// 246.797 us; speedup vs baseline: 2.9294x; 2.9294x over previous
//
#include <hip/hip_runtime.h>
#include <math.h>

#define BATCH 4
#define DLAT 16
#define KCB 8192
#define HLAT 122
#define PIX (HLAT*HLAT)          // 14884
#define NLAT (BATCH*PIX)         // 59536
#define NT32 (KCB/32)            // 256 codeword tiles (32 cols each)
#define ROWSB 32                 // rows per vq block
#define NVQBLK 1861              // ceil(59536/32)
#define NWAVE 4                  // waves per vq block
#define TW (NT32/NWAVE)          // 64 tiles per wave per pass
#define CAPW 1024                // candidate list capacity per block
#define NCONVBLK 3721            // conv3_last blocks (= 952576/256)

typedef _Float16 half8 __attribute__((ext_vector_type(8)));
typedef float f32x16 __attribute__((ext_vector_type(16)));

// jax.nn.selu in fp32: scale * where(x>0, x, alpha*expm1(x))
__device__ __forceinline__ float selu_np(float x) {
    const float scale = 1.0507009873554805f, alpha = 1.6732632423543772f;
    if (x > 0.f) return __fmul_rn(scale, x);
    return __fmul_rn(scale, __fmul_rn(alpha, expm1f(x)));
}

// ---- fp32 VALID 3x3 conv, NCHW/OIHW, np-order: acc=0; fma over (c,p,q); +bias after ----
template<int CI, int CO, int HIN, int WIN, bool DOSELU>
__global__ void conv3x3_np(const float* __restrict__ in, const float* __restrict__ w,
                           const float* __restrict__ bias, float* __restrict__ out) {
    constexpr int HO = HIN - 2, WO = WIN - 2;
    int tid = blockIdx.x * blockDim.x + threadIdx.x;
    constexpr int total = BATCH * CO * HO * WO;
    if (tid >= total) return;
    int j = tid % WO; int t = tid / WO;
    int i = t % HO;   t /= HO;
    int o = t % CO;   int b = t / CO;
    float acc = 0.f;
    for (int c = 0; c < CI; ++c) {
        const float* ip = in + ((b * CI + c) * HIN + i) * WIN + j;
        const float* wp = w + ((o * CI + c) * 3) * 3;
        #pragma unroll
        for (int p = 0; p < 3; ++p)
            #pragma unroll
            for (int q = 0; q < 3; ++q)
                acc = __fmaf_rn(ip[p * WIN + q], wp[p * 3 + q], acc);
    }
    acc = __fadd_rn(acc, bias[o]);
    out[tid] = DOSELU ? selu_np(acc) : acc;
}

// ---- last encoder conv, o-fastest mapping: coalesced zf/zh, block-local max ----
__global__ void conv3_last_np(const float* __restrict__ in, const float* __restrict__ w,
                              const float* __restrict__ bias, float* __restrict__ zf,
                              _Float16* __restrict__ zh, float* __restrict__ blockmax) {
    constexpr int CI = 8, HIN = 124, WIN = 124, WO = 122;
    __shared__ float sred[4];
    int tid = blockIdx.x * 256 + threadIdx.x;   // 3721*256 = 952576 exact
    int o  = tid & 15;
    int pp = tid >> 4;                          // latent row 0..59535
    int b = pp / PIX, pix = pp % PIX;
    int i = pix / WO, j = pix % WO;
    float acc = 0.f;
    for (int c = 0; c < CI; ++c) {
        const float* ip = in + ((b * CI + c) * HIN + i) * WIN + j;
        const float* wp = w + ((o * CI + c) * 3) * 3;
        #pragma unroll
        for (int p = 0; p < 3; ++p)
            #pragma unroll
            for (int q = 0; q < 3; ++q)
                acc = __fmaf_rn(ip[p * WIN + q], wp[p * 3 + q], acc);
    }
    acc = __fadd_rn(acc, bias[o]);
    zf[tid] = acc;                 // = zf[pp*16+o], coalesced
    zh[tid] = (_Float16)acc;
    float m = fabsf(acc);
    #pragma unroll
    for (int off = 32; off; off >>= 1) m = fmaxf(m, __shfl_xor(m, off));
    if ((threadIdx.x & 63) == 0) sred[threadIdx.x >> 6] = m;
    __syncthreads();
    if (threadIdx.x == 0)
        blockmax[blockIdx.x] = fmaxf(fmaxf(sred[0], sred[1]), fmaxf(sred[2], sred[3]));
}

// ---- reduce blockmax -> scal[0]; also init scal[1]=0 (runs before cbprep) ----
__global__ void reduce_zmax(const float* __restrict__ bm, unsigned* __restrict__ scal) {
    __shared__ float sred[4];
    float m = 0.f;
    for (int i = threadIdx.x; i < NCONVBLK; i += 256) m = fmaxf(m, bm[i]);
    #pragma unroll
    for (int off = 32; off; off >>= 1) m = fmaxf(m, __shfl_xor(m, off));
    if ((threadIdx.x & 63) == 0) sred[threadIdx.x >> 6] = m;
    __syncthreads();
    if (threadIdx.x == 0)
        scal[0] = __float_as_uint(fmaxf(fmaxf(sred[0], sred[1]), fmaxf(sred[2], sred[3])));
    if (threadIdx.x == 1) scal[1] = 0u;
}

// ---- numpy pairwise-16 sum of squares ----
__device__ __forceinline__ float pairwise16_sq(const float* v) {
    float a[16];
    #pragma unroll
    for (int d = 0; d < 16; ++d) a[d] = __fmul_rn(v[d], v[d]);
    float r0 = __fadd_rn(a[0], a[8]),  r1 = __fadd_rn(a[1], a[9]);
    float r2 = __fadd_rn(a[2], a[10]), r3 = __fadd_rn(a[3], a[11]);
    float r4 = __fadd_rn(a[4], a[12]), r5 = __fadd_rn(a[5], a[13]);
    float r6 = __fadd_rn(a[6], a[14]), r7 = __fadd_rn(a[7], a[15]);
    return __fadd_rn(__fadd_rn(__fadd_rn(r0, r1), __fadd_rn(r2, r3)),
                     __fadd_rn(__fadd_rn(r4, r5), __fadd_rn(r6, r7)));
}

__device__ __forceinline__ void load16(const float* __restrict__ p, float* v) {
    const float4* r = (const float4*)p;
    float4 v0 = r[0], v1 = r[1], v2 = r[2], v3 = r[3];
    v[0]=v0.x; v[1]=v0.y; v[2]=v0.z; v[3]=v0.w;
    v[4]=v1.x; v[5]=v1.y; v[6]=v1.z; v[7]=v1.w;
    v[8]=v2.x; v[9]=v2.y; v[10]=v2.z; v[11]=v2.w;
    v[12]=v3.x; v[13]=v3.y; v[14]=v3.z; v[15]=v3.w;
}

__device__ __forceinline__ float np_d2(const float* zr, float A, const float* e16, float cnk) {
    float g = 0.f;
    #pragma unroll
    for (int d = 0; d < 16; ++d) g = __fmaf_rn(zr[d], e16[d], g);
    return __fadd_rn(__fmaf_rn(-2.f, g, A), cnk);
}

// ---- codebook prep: cn, cnT = -cn/2 transposed [col][tile], max||e||^2, B-frag ----
__global__ void cbprep(const float* __restrict__ cb, float* __restrict__ cn,
                       float* __restrict__ cnT,
                       _Float16* __restrict__ cbB, unsigned* __restrict__ scal) {
    int k = blockIdx.x * 256 + threadIdx.x;   // 32 x 256 = 8192
    float v[16];
    load16(cb + (size_t)k * DLAT, v);
    float C = pairwise16_sq(v);
    cn[k] = C;
    int tile = k >> 5, col = k & 31;
    cnT[col * NT32 + tile] = __fmul_rn(-0.5f, C);
    float m = C;
    #pragma unroll
    for (int off = 32; off; off >>= 1) m = fmaxf(m, __shfl_xor(m, off));
    if ((threadIdx.x & 63) == 0) atomicMax(&scal[1], __float_as_uint(m));
    #pragma unroll
    for (int d = 0; d < 16; ++d) {
        int ln = (d >> 3) * 32 + col;          // lane 0..63
        cbB[(size_t)tile * 512 + ln * 8 + (d & 7)] = (_Float16)v[d];
    }
}

// D-reg -> row-in-group for mfma_f32_32x32x16 (col = lane&31)
#define DROW(reg, lanehi) (((reg) & 3) + 8 * ((reg) >> 2) + 4 * (lanehi))

// ---- VQ: 32x32x16 MFMA screen with C = -cn/2 folded (D = z.e - cn/2, s = -2D) ----
__global__ __launch_bounds__(256, 4) void vq_mfma(
        const _Float16* __restrict__ zh, const float* __restrict__ zf,
        const _Float16* __restrict__ cbB, const float* __restrict__ cn,
        const float* __restrict__ cnT,
        const float* __restrict__ cb, const unsigned* __restrict__ scal,
        float* __restrict__ idx_out, float* __restrict__ zq) {
    __shared__ unsigned list[CAPW];
    __shared__ float resd[CAPW];
    __shared__ float smax[NWAVE][ROWSB];
    __shared__ unsigned lcnt;
    const int tid = threadIdx.x;
    const int w = tid >> 6, lane = tid & 63;
    const int lanehi = lane >> 5;
    const int col = lane & 31;
    const int R0 = blockIdx.x * ROWSB;
    if (tid == 0) lcnt = 0;

    // A-frag: row = R0 + (lane&31), k = lanehi*8 + i
    int ar = R0 + col;
    if (ar >= NLAT) ar = NLAT - 1;
    half8 a = *(const half8*)(zh + (size_t)ar * DLAT + lanehi * 8);

    // rigorous screening threshold (same formula as R13, HW-validated)
    float zmaxf = __uint_as_float(scal[0]);
    float en    = sqrtf(__uint_as_float(scal[1]));
    float errG  = 4.f * zmaxf * en * 9.765625e-4f * 1.03f
                + 6.104e-5f * (16.f * zmaxf + 4.f * en);
    float slack = (16.f * zmaxf * zmaxf + 8.f * zmaxf * en + en * en) * 1.2e-7f;
    float DELTA = 4.f * errG + 2.f * slack + 1e-6f;

    const int t0 = w * TW, t1 = t0 + TW;
    const float* cnTl = cnT + (size_t)col * NT32;

    // ---- pass A: running MAX of D over the wave's tile slice ----
    float mm[16];
    #pragma unroll
    for (int r = 0; r < 16; ++r) mm[r] = -INFINITY;

    for (int t = t0; t < t1; t += 4) {
        float4 cn4 = *(const float4*)(cnTl + t);
        #pragma unroll
        for (int u = 0; u < 4; ++u) {
            half8 b = *(const half8*)(cbB + (size_t)(t + u) * 512 + lane * 8);
            float cnv = ((const float*)&cn4)[u];
            f32x16 cvec;
            #pragma unroll
            for (int j = 0; j < 16; ++j) cvec[j] = cnv;
            f32x16 D = __builtin_amdgcn_mfma_f32_32x32x16_f16(a, b, cvec, 0, 0, 0);
            #pragma unroll
            for (int r = 0; r < 16; ++r) mm[r] = fmaxf(mm[r], D[r]);
        }
    }
    // reduce MAX over the 32 cols (lanes sharing lanehi)
    #pragma unroll
    for (int r = 0; r < 16; ++r) {
        float v = mm[r];
        v = fmaxf(v, __shfl_xor(v, 1));
        v = fmaxf(v, __shfl_xor(v, 2));
        v = fmaxf(v, __shfl_xor(v, 4));
        v = fmaxf(v, __shfl_xor(v, 8));
        v = fmaxf(v, __shfl_xor(v, 16));
        mm[r] = v;
    }
    // combine across waves
    if (col == 0) {
        #pragma unroll
        for (int r = 0; r < 16; ++r)
            smax[w][DROW(r, lanehi)] = mm[r];
    }
    __syncthreads();
    #pragma unroll
    for (int r = 0; r < 16; ++r) {
        int row = DROW(r, lanehi);
        float v = -INFINITY;
        #pragma unroll
        for (int ww = 0; ww < NWAVE; ++ww) v = fmaxf(v, smax[ww][row]);
        mm[r] = v - 0.5f * DELTA;   // threshold: D >= Dmax - DELTA/2  <=>  s <= smin + DELTA
    }

    // ---- pass B: append candidates D >= threshold ----
    for (int t = t0; t < t1; t += 4) {
        float4 cn4 = *(const float4*)(cnTl + t);
        #pragma unroll
        for (int u = 0; u < 4; ++u) {
            half8 b = *(const half8*)(cbB + (size_t)(t + u) * 512 + lane * 8);
            float cnv = ((const float*)&cn4)[u];
            f32x16 cvec;
            #pragma unroll
            for (int j = 0; j < 16; ++j) cvec[j] = cnv;
            f32x16 D = __builtin_amdgcn_mfma_f32_32x32x16_f16(a, b, cvec, 0, 0, 0);
            bool anyp = false;
            #pragma unroll
            for (int r = 0; r < 16; ++r)
                anyp |= (D[r] >= mm[r]);
            if (__ballot(anyp)) {   // rare
                #pragma unroll
                for (int r = 0; r < 16; ++r) {
                    bool pred = (D[r] >= mm[r]);
                    unsigned long long bal = __ballot(pred);
                    if (bal) {
                        unsigned nb = (unsigned)__popcll(bal);
                        unsigned base = 0;
                        if (lane == 0) base = atomicAdd(&lcnt, nb);
                        base = __shfl(base, 0);
                        unsigned pos = base + (unsigned)__popcll(bal & ((1ull << lane) - 1ull));
                        if (pred && pos < CAPW) {
                            unsigned rs = (unsigned)DROW(r, lanehi);
                            list[pos] = (rs << 13) | (unsigned)((t + u) * 32 + col);
                        }
                    }
                }
            }
        }
    }
    __syncthreads();
    unsigned cnt = lcnt;

    // ---- pass C: exact np-fp32 rescore (all 256 threads) ----
    if (cnt <= CAPW) {
        for (unsigned i = tid; i < cnt; i += 256) {
            unsigned e = list[i];
            int n = R0 + (int)(e >> 13);
            if (n >= NLAT) n = NLAT - 1;
            int k = (int)(e & 8191);
            float zr[16], e16[16];
            load16(zf + (size_t)n * DLAT, zr);
            float A = pairwise16_sq(zr);
            load16(cb + (size_t)k * DLAT, e16);
            resd[i] = np_d2(zr, A, e16, cn[k]);
        }
    }
    __syncthreads();

    // ---- selection: tid = row-in-block (first-occurrence tie on k) ----
    if (tid < ROWSB) {
        int r = R0 + tid;
        if (r < NLAT) {
            float bd = INFINITY; int bk = 0x7fffffff;
            if (cnt <= CAPW) {
                for (unsigned i = 0; i < cnt; ++i) {
                    unsigned e = list[i];
                    if ((int)(e >> 13) == tid) {
                        float d2 = resd[i]; int k = (int)(e & 8191);
                        if (d2 < bd || (d2 == bd && k < bk)) { bd = d2; bk = k; }
                    }
                }
            } else {
                // overflow fallback (unreachable in practice): exact per-lane full scan
                float zr[16];
                load16(zf + (size_t)r * DLAT, zr);
                float A = pairwise16_sq(zr);
                for (int k = 0; k < KCB; ++k) {
                    float e16[16];
                    load16(cb + (size_t)k * DLAT, e16);
                    float d2 = np_d2(zr, A, e16, cn[k]);
                    if (d2 < bd) { bd = d2; bk = k; }
                }
            }
            idx_out[r] = (float)bk;
            int b = r / PIX, pix = r % PIX;
            const float* e = cb + (size_t)bk * DLAT;
            #pragma unroll
            for (int d = 0; d < DLAT; ++d) zq[((size_t)(b * DLAT + d)) * PIX + pix] = e[d];
        }
    }
}

// ---- fp32 transpose conv (stride1, k3, pad2), weights (CI,CO,3,3), interior fast path ----
template<int CI, int CO, int HIN, int WIN, bool DOSELU>
__global__ void convt3x3(const float* __restrict__ in, const float* __restrict__ w,
                         const float* __restrict__ bias, float* __restrict__ out) {
    constexpr int HO = HIN + 2, WO = WIN + 2;
    int tid = blockIdx.x * blockDim.x + threadIdx.x;
    constexpr int total = BATCH * CO * HO * WO;
    if (tid >= total) return;
    int j = tid % WO; int t = tid / WO;
    int i = t % HO;   t /= HO;
    int o = t % CO;   int b = t / CO;
    float acc = bias[o];
    if (i >= 2 && i < HIN && j >= 2 && j < WIN) {
        // interior: all 9 taps in-bounds
        const float* ip0 = in + (((size_t)b * CI) * HIN + (i - 2)) * WIN + (j - 2);
        for (int c = 0; c < CI; ++c) {
            const float* ip = ip0 + (size_t)c * HIN * WIN;
            const float* wp = w + ((c * CO + o) * 3) * 3;
            #pragma unroll
            for (int p = 0; p < 3; ++p)
                #pragma unroll
                for (int q = 0; q < 3; ++q)
                    acc += ip[p * WIN + q] * wp[(2 - p) * 3 + (2 - q)];
        }
    } else {
        for (int c = 0; c < CI; ++c) {
            const float* ip = in + ((b * CI + c) * HIN) * WIN;
            const float* wp = w + ((c * CO + o) * 3) * 3;
            #pragma unroll
            for (int p = 0; p < 3; ++p) {
                int ii = i + p - 2;
                if (ii < 0 || ii >= HIN) continue;
                #pragma unroll
                for (int q = 0; q < 3; ++q) {
                    int jj = j + q - 2;
                    if (jj < 0 || jj >= WIN) continue;
                    acc += ip[ii * WIN + jj] * wp[(2 - p) * 3 + (2 - q)];
                }
            }
        }
    }
    const float scale = 1.0507009873554805f, alpha = 1.6732632423543772f;
    out[tid] = DOSELU ? (acc > 0.f ? scale * acc : scale * alpha * (expf(acc) - 1.f)) : acc;
}

extern "C" void kernel_launch(void* const* d_in, const int* in_sizes, int n_in,
                              void* d_out, int out_size, void* d_ws, size_t ws_size,
                              hipStream_t stream) {
    const float* x   = (const float*)d_in[0];
    const float* ew1 = (const float*)d_in[1];  const float* eb1 = (const float*)d_in[2];
    const float* ew2 = (const float*)d_in[3];  const float* eb2 = (const float*)d_in[4];
    const float* ew3 = (const float*)d_in[5];  const float* eb3 = (const float*)d_in[6];
    const float* dw1 = (const float*)d_in[7];  const float* db1 = (const float*)d_in[8];
    const float* dw2 = (const float*)d_in[9];  const float* db2 = (const float*)d_in[10];
    const float* dw3 = (const float*)d_in[11]; const float* db3 = (const float*)d_in[12];
    const float* cb  = (const float*)d_in[13];

    float* out_y   = (float*)d_out;                 // 196608
    float* out_idx = (float*)d_out + 196608;        // 59536 (as float)

    // ---- workspace (float offsets); ~12.3 MiB ----
    float*     ws   = (float*)d_ws;
    float*     zf   = ws;                         // [0 .. 952576)
    float*     e1   = ws + 952576;                // 254016
    float*     e2   = ws + 1206592;               // 492032 (ends 1698624)
    float*     fZq  = ws + 952576;                // decoder phase (ends 1905152)
    float*     fB   = ws + 1905152;               // 492032 (ends 2397184)
    float*     fA   = ws + 2397184;               // 254016 (ends 2651200)
    _Float16*  zh   = (_Float16*)(ws + 2651200);  // 952576 halves
    _Float16*  cbB  = (_Float16*)(ws + 3127488);  // 131072 halves
    float*     cn   = ws + 3193024;               // 8192
    float*     cnT  = ws + 3201216;               // 8192 (= -cn/2, [col][tile])
    unsigned*  scal = (unsigned*)(ws + 3209408);  // 2
    float*     bmax = ws + 3209410;               // 3721

    const int TPB = 256;

    // encoder (fp32, np-order replica)
    conv3x3_np<3, 4, 128, 128, true ><<<993,  TPB, 0, stream>>>(x,  ew1, eb1, e1);
    conv3x3_np<4, 8, 126, 126, true ><<<1922, TPB, 0, stream>>>(e1, ew2, eb2, e2);
    conv3_last_np<<<NCONVBLK, TPB, 0, stream>>>(e2, ew3, eb3, zf, zh, bmax);
    reduce_zmax<<<1, TPB, 0, stream>>>(bmax, scal);   // also inits scal[1]

    // codebook prep + VQ (32x32x16 MFMA, C = -cn/2 folded; 2-pass screen + exact rescore)
    cbprep<<<32, TPB, 0, stream>>>(cb, cn, cnT, cbB, scal);
    vq_mfma<<<NVQBLK, TPB, 0, stream>>>(zh, zf, cbB, cn, cnT, cb, scal, out_idx, fZq);

    // decoder (fp32)
    convt3x3<16, 8, 122, 122, true ><<<1922, TPB, 0, stream>>>(fZq, dw1, db1, fB);
    convt3x3<8, 4, 124, 124, true ><<<993,  TPB, 0, stream>>>(fB,  dw2, db2, fA);
    convt3x3<4, 3, 126, 126, false><<<768,  TPB, 0, stream>>>(fA,  dw3, db3, out_y);
}

// Round 23
// 222.539 us; speedup vs baseline: 3.2487x; 1.1090x over previous
//
#include <hip/hip_runtime.h>
#include <math.h>

#define BATCH 4
#define DLAT 16
#define KCB 8192
#define HLAT 122
#define PIX (HLAT*HLAT)          // 14884
#define NLAT (BATCH*PIX)         // 59536
#define NT32 (KCB/32)            // 256 codeword tiles (32 cols each)
#define ROWSB 32                 // rows per vq block
#define NVQBLK 1861              // ceil(59536/32)
#define NWAVE 4                  // waves per vq block
#define TW (NT32/NWAVE)          // 64 tiles per wave per pass
#define CAPW 1024                // candidate list capacity per block
#define NCONVBLK 3721            // conv3_last blocks (= 952576/256)

typedef _Float16 half8 __attribute__((ext_vector_type(8)));
typedef float f32x16 __attribute__((ext_vector_type(16)));

// jax.nn.selu in fp32: scale * where(x>0, x, alpha*expm1(x))
__device__ __forceinline__ float selu_np(float x) {
    const float scale = 1.0507009873554805f, alpha = 1.6732632423543772f;
    if (x > 0.f) return __fmul_rn(scale, x);
    return __fmul_rn(scale, __fmul_rn(alpha, expm1f(x)));
}

// ---- fp32 VALID 3x3 conv, NCHW/OIHW, np-order: acc=0; fma over (c,p,q); +bias after ----
template<int CI, int CO, int HIN, int WIN, bool DOSELU>
__global__ void conv3x3_np(const float* __restrict__ in, const float* __restrict__ w,
                           const float* __restrict__ bias, float* __restrict__ out) {
    constexpr int HO = HIN - 2, WO = WIN - 2;
    int tid = blockIdx.x * blockDim.x + threadIdx.x;
    constexpr int total = BATCH * CO * HO * WO;
    if (tid >= total) return;
    int j = tid % WO; int t = tid / WO;
    int i = t % HO;   t /= HO;
    int o = t % CO;   int b = t / CO;
    float acc = 0.f;
    for (int c = 0; c < CI; ++c) {
        const float* ip = in + ((b * CI + c) * HIN + i) * WIN + j;
        const float* wp = w + ((o * CI + c) * 3) * 3;
        #pragma unroll
        for (int p = 0; p < 3; ++p)
            #pragma unroll
            for (int q = 0; q < 3; ++q)
                acc = __fmaf_rn(ip[p * WIN + q], wp[p * 3 + q], acc);
    }
    acc = __fadd_rn(acc, bias[o]);
    out[tid] = DOSELU ? selu_np(acc) : acc;
}

// ---- last encoder conv, o-fastest mapping: coalesced zf/zh, block-local max ----
__global__ void conv3_last_np(const float* __restrict__ in, const float* __restrict__ w,
                              const float* __restrict__ bias, float* __restrict__ zf,
                              _Float16* __restrict__ zh, float* __restrict__ blockmax) {
    constexpr int CI = 8, HIN = 124, WIN = 124, WO = 122;
    __shared__ float sred[4];
    int tid = blockIdx.x * 256 + threadIdx.x;   // 3721*256 = 952576 exact
    int o  = tid & 15;
    int pp = tid >> 4;                          // latent row 0..59535
    int b = pp / PIX, pix = pp % PIX;
    int i = pix / WO, j = pix % WO;
    float acc = 0.f;
    for (int c = 0; c < CI; ++c) {
        const float* ip = in + ((b * CI + c) * HIN + i) * WIN + j;
        const float* wp = w + ((o * CI + c) * 3) * 3;
        #pragma unroll
        for (int p = 0; p < 3; ++p)
            #pragma unroll
            for (int q = 0; q < 3; ++q)
                acc = __fmaf_rn(ip[p * WIN + q], wp[p * 3 + q], acc);
    }
    acc = __fadd_rn(acc, bias[o]);
    zf[tid] = acc;                 // = zf[pp*16+o], coalesced
    zh[tid] = (_Float16)acc;
    float m = fabsf(acc);
    #pragma unroll
    for (int off = 32; off; off >>= 1) m = fmaxf(m, __shfl_xor(m, off));
    if ((threadIdx.x & 63) == 0) sred[threadIdx.x >> 6] = m;
    __syncthreads();
    if (threadIdx.x == 0)
        blockmax[blockIdx.x] = fmaxf(fmaxf(sred[0], sred[1]), fmaxf(sred[2], sred[3]));
}

// ---- reduce blockmax -> scal[0]; also init scal[1]=0 (runs before cbprep) ----
__global__ void reduce_zmax(const float* __restrict__ bm, unsigned* __restrict__ scal) {
    __shared__ float sred[4];
    float m = 0.f;
    for (int i = threadIdx.x; i < NCONVBLK; i += 256) m = fmaxf(m, bm[i]);
    #pragma unroll
    for (int off = 32; off; off >>= 1) m = fmaxf(m, __shfl_xor(m, off));
    if ((threadIdx.x & 63) == 0) sred[threadIdx.x >> 6] = m;
    __syncthreads();
    if (threadIdx.x == 0)
        scal[0] = __float_as_uint(fmaxf(fmaxf(sred[0], sred[1]), fmaxf(sred[2], sred[3])));
    if (threadIdx.x == 1) scal[1] = 0u;
}

// ---- numpy pairwise-16 sum of squares ----
__device__ __forceinline__ float pairwise16_sq(const float* v) {
    float a[16];
    #pragma unroll
    for (int d = 0; d < 16; ++d) a[d] = __fmul_rn(v[d], v[d]);
    float r0 = __fadd_rn(a[0], a[8]),  r1 = __fadd_rn(a[1], a[9]);
    float r2 = __fadd_rn(a[2], a[10]), r3 = __fadd_rn(a[3], a[11]);
    float r4 = __fadd_rn(a[4], a[12]), r5 = __fadd_rn(a[5], a[13]);
    float r6 = __fadd_rn(a[6], a[14]), r7 = __fadd_rn(a[7], a[15]);
    return __fadd_rn(__fadd_rn(__fadd_rn(r0, r1), __fadd_rn(r2, r3)),
                     __fadd_rn(__fadd_rn(r4, r5), __fadd_rn(r6, r7)));
}

__device__ __forceinline__ void load16(const float* __restrict__ p, float* v) {
    const float4* r = (const float4*)p;
    float4 v0 = r[0], v1 = r[1], v2 = r[2], v3 = r[3];
    v[0]=v0.x; v[1]=v0.y; v[2]=v0.z; v[3]=v0.w;
    v[4]=v1.x; v[5]=v1.y; v[6]=v1.z; v[7]=v1.w;
    v[8]=v2.x; v[9]=v2.y; v[10]=v2.z; v[11]=v2.w;
    v[12]=v3.x; v[13]=v3.y; v[14]=v3.z; v[15]=v3.w;
}

__device__ __forceinline__ float np_d2(const float* zr, float A, const float* e16, float cnk) {
    float g = 0.f;
    #pragma unroll
    for (int d = 0; d < 16; ++d) g = __fmaf_rn(zr[d], e16[d], g);
    return __fadd_rn(__fmaf_rn(-2.f, g, A), cnk);
}

// ---- codebook prep: cn, cnT = -cn/2 transposed [col][tile], max||e||^2, B-frag ----
__global__ void cbprep(const float* __restrict__ cb, float* __restrict__ cn,
                       float* __restrict__ cnT,
                       _Float16* __restrict__ cbB, unsigned* __restrict__ scal) {
    int k = blockIdx.x * 256 + threadIdx.x;   // 32 x 256 = 8192
    float v[16];
    load16(cb + (size_t)k * DLAT, v);
    float C = pairwise16_sq(v);
    cn[k] = C;
    int tile = k >> 5, col = k & 31;
    cnT[col * NT32 + tile] = __fmul_rn(-0.5f, C);
    float m = C;
    #pragma unroll
    for (int off = 32; off; off >>= 1) m = fmaxf(m, __shfl_xor(m, off));
    if ((threadIdx.x & 63) == 0) atomicMax(&scal[1], __float_as_uint(m));
    #pragma unroll
    for (int d = 0; d < 16; ++d) {
        int ln = (d >> 3) * 32 + col;          // lane 0..63
        cbB[(size_t)tile * 512 + ln * 8 + (d & 7)] = (_Float16)v[d];
    }
}

// D-reg -> row-in-group for mfma_f32_32x32x16 (col = lane&31)
#define DROW(reg, lanehi) (((reg) & 3) + 8 * ((reg) >> 2) + 4 * (lanehi))

// ---- VQ: 32x32x16 MFMA screen with C = -cn/2 folded (D = z.e - cn/2, s = -2D) ----
__global__ __launch_bounds__(256, 4) void vq_mfma(
        const _Float16* __restrict__ zh, const float* __restrict__ zf,
        const _Float16* __restrict__ cbB, const float* __restrict__ cn,
        const float* __restrict__ cnT,
        const float* __restrict__ cb, const unsigned* __restrict__ scal,
        float* __restrict__ idx_out, float* __restrict__ zq) {
    __shared__ unsigned list[CAPW];
    __shared__ float resd[CAPW];
    __shared__ float smax[NWAVE][ROWSB];
    __shared__ unsigned lcnt;
    const int tid = threadIdx.x;
    const int w = tid >> 6, lane = tid & 63;
    const int lanehi = lane >> 5;
    const int col = lane & 31;
    const int R0 = blockIdx.x * ROWSB;
    if (tid == 0) lcnt = 0;

    // A-frag: row = R0 + (lane&31), k = lanehi*8 + i
    int ar = R0 + col;
    if (ar >= NLAT) ar = NLAT - 1;
    half8 a = *(const half8*)(zh + (size_t)ar * DLAT + lanehi * 8);

    // rigorous screening threshold (same formula as R13, HW-validated)
    float zmaxf = __uint_as_float(scal[0]);
    float en    = sqrtf(__uint_as_float(scal[1]));
    float errG  = 4.f * zmaxf * en * 9.765625e-4f * 1.03f
                + 6.104e-5f * (16.f * zmaxf + 4.f * en);
    float slack = (16.f * zmaxf * zmaxf + 8.f * zmaxf * en + en * en) * 1.2e-7f;
    float DELTA = 4.f * errG + 2.f * slack + 1e-6f;

    const int t0 = w * TW, t1 = t0 + TW;
    const float* cnTl = cnT + (size_t)col * NT32;

    // ---- pass A: running MAX of D over the wave's tile slice ----
    float mm[16];
    #pragma unroll
    for (int r = 0; r < 16; ++r) mm[r] = -INFINITY;

    for (int t = t0; t < t1; t += 4) {
        float4 cn4 = *(const float4*)(cnTl + t);
        #pragma unroll
        for (int u = 0; u < 4; ++u) {
            half8 b = *(const half8*)(cbB + (size_t)(t + u) * 512 + lane * 8);
            float cnv = ((const float*)&cn4)[u];
            f32x16 cvec;
            #pragma unroll
            for (int j = 0; j < 16; ++j) cvec[j] = cnv;
            f32x16 D = __builtin_amdgcn_mfma_f32_32x32x16_f16(a, b, cvec, 0, 0, 0);
            #pragma unroll
            for (int r = 0; r < 16; ++r) mm[r] = fmaxf(mm[r], D[r]);
        }
    }
    // reduce MAX over the 32 cols (lanes sharing lanehi)
    #pragma unroll
    for (int r = 0; r < 16; ++r) {
        float v = mm[r];
        v = fmaxf(v, __shfl_xor(v, 1));
        v = fmaxf(v, __shfl_xor(v, 2));
        v = fmaxf(v, __shfl_xor(v, 4));
        v = fmaxf(v, __shfl_xor(v, 8));
        v = fmaxf(v, __shfl_xor(v, 16));
        mm[r] = v;
    }
    // combine across waves
    if (col == 0) {
        #pragma unroll
        for (int r = 0; r < 16; ++r)
            smax[w][DROW(r, lanehi)] = mm[r];
    }
    __syncthreads();
    #pragma unroll
    for (int r = 0; r < 16; ++r) {
        int row = DROW(r, lanehi);
        float v = -INFINITY;
        #pragma unroll
        for (int ww = 0; ww < NWAVE; ++ww) v = fmaxf(v, smax[ww][row]);
        mm[r] = v - 0.5f * DELTA;   // threshold: D >= Dmax - DELTA/2  <=>  s <= smin + DELTA
    }

    // ---- pass B: append candidates D >= threshold ----
    for (int t = t0; t < t1; t += 4) {
        float4 cn4 = *(const float4*)(cnTl + t);
        #pragma unroll
        for (int u = 0; u < 4; ++u) {
            half8 b = *(const half8*)(cbB + (size_t)(t + u) * 512 + lane * 8);
            float cnv = ((const float*)&cn4)[u];
            f32x16 cvec;
            #pragma unroll
            for (int j = 0; j < 16; ++j) cvec[j] = cnv;
            f32x16 D = __builtin_amdgcn_mfma_f32_32x32x16_f16(a, b, cvec, 0, 0, 0);
            bool anyp = false;
            #pragma unroll
            for (int r = 0; r < 16; ++r)
                anyp |= (D[r] >= mm[r]);
            if (__ballot(anyp)) {   // rare
                #pragma unroll
                for (int r = 0; r < 16; ++r) {
                    bool pred = (D[r] >= mm[r]);
                    unsigned long long bal = __ballot(pred);
                    if (bal) {
                        unsigned nb = (unsigned)__popcll(bal);
                        unsigned base = 0;
                        if (lane == 0) base = atomicAdd(&lcnt, nb);
                        base = __shfl(base, 0);
                        unsigned pos = base + (unsigned)__popcll(bal & ((1ull << lane) - 1ull));
                        if (pred && pos < CAPW) {
                            unsigned rs = (unsigned)DROW(r, lanehi);
                            list[pos] = (rs << 13) | (unsigned)((t + u) * 32 + col);
                        }
                    }
                }
            }
        }
    }
    __syncthreads();
    unsigned cnt = lcnt;

    // ---- pass C: exact np-fp32 rescore (all 256 threads) ----
    if (cnt <= CAPW) {
        for (unsigned i = tid; i < cnt; i += 256) {
            unsigned e = list[i];
            int n = R0 + (int)(e >> 13);
            if (n >= NLAT) n = NLAT - 1;
            int k = (int)(e & 8191);
            float zr[16], e16[16];
            load16(zf + (size_t)n * DLAT, zr);
            float A = pairwise16_sq(zr);
            load16(cb + (size_t)k * DLAT, e16);
            resd[i] = np_d2(zr, A, e16, cn[k]);
        }
    }
    __syncthreads();

    // ---- selection: tid = row-in-block (first-occurrence tie on k) ----
    if (tid < ROWSB) {
        int r = R0 + tid;
        if (r < NLAT) {
            float bd = INFINITY; int bk = 0x7fffffff;
            if (cnt <= CAPW) {
                for (unsigned i = 0; i < cnt; ++i) {
                    unsigned e = list[i];
                    if ((int)(e >> 13) == tid) {
                        float d2 = resd[i]; int k = (int)(e & 8191);
                        if (d2 < bd || (d2 == bd && k < bk)) { bd = d2; bk = k; }
                    }
                }
            } else {
                // overflow fallback (unreachable in practice): exact per-lane full scan
                float zr[16];
                load16(zf + (size_t)r * DLAT, zr);
                float A = pairwise16_sq(zr);
                for (int k = 0; k < KCB; ++k) {
                    float e16[16];
                    load16(cb + (size_t)k * DLAT, e16);
                    float d2 = np_d2(zr, A, e16, cn[k]);
                    if (d2 < bd) { bd = d2; bk = k; }
                }
            }
            idx_out[r] = (float)bk;
            int b = r / PIX, pix = r % PIX;
            const float* e = cb + (size_t)bk * DLAT;
            #pragma unroll
            for (int d = 0; d < DLAT; ++d) zq[((size_t)(b * DLAT + d)) * PIX + pix] = e[d];
        }
    }
}

// ---- fp32 transpose conv (stride1, k3, pad2), weights (CI,CO,3,3) ----
template<int CI, int CO, int HIN, int WIN, bool DOSELU>
__global__ void convt3x3(const float* __restrict__ in, const float* __restrict__ w,
                         const float* __restrict__ bias, float* __restrict__ out) {
    constexpr int HO = HIN + 2, WO = WIN + 2;
    int tid = blockIdx.x * blockDim.x + threadIdx.x;
    constexpr int total = BATCH * CO * HO * WO;
    if (tid >= total) return;
    int j = tid % WO; int t = tid / WO;
    int i = t % HO;   t /= HO;
    int o = t % CO;   int b = t / CO;
    float acc = bias[o];
    for (int c = 0; c < CI; ++c) {
        const float* ip = in + ((b * CI + c) * HIN) * WIN;
        const float* wp = w + ((c * CO + o) * 3) * 3;
        #pragma unroll
        for (int p = 0; p < 3; ++p) {
            int ii = i + p - 2;
            if (ii < 0 || ii >= HIN) continue;
            #pragma unroll
            for (int q = 0; q < 3; ++q) {
                int jj = j + q - 2;
                if (jj < 0 || jj >= WIN) continue;
                acc += ip[ii * WIN + jj] * wp[(2 - p) * 3 + (2 - q)];
            }
        }
    }
    const float scale = 1.0507009873554805f, alpha = 1.6732632423543772f;
    out[tid] = DOSELU ? (acc > 0.f ? scale * acc : scale * alpha * (expf(acc) - 1.f)) : acc;
}

extern "C" void kernel_launch(void* const* d_in, const int* in_sizes, int n_in,
                              void* d_out, int out_size, void* d_ws, size_t ws_size,
                              hipStream_t stream) {
    const float* x   = (const float*)d_in[0];
    const float* ew1 = (const float*)d_in[1];  const float* eb1 = (const float*)d_in[2];
    const float* ew2 = (const float*)d_in[3];  const float* eb2 = (const float*)d_in[4];
    const float* ew3 = (const float*)d_in[5];  const float* eb3 = (const float*)d_in[6];
    const float* dw1 = (const float*)d_in[7];  const float* db1 = (const float*)d_in[8];
    const float* dw2 = (const float*)d_in[9];  const float* db2 = (const float*)d_in[10];
    const float* dw3 = (const float*)d_in[11]; const float* db3 = (const float*)d_in[12];
    const float* cb  = (const float*)d_in[13];

    float* out_y   = (float*)d_out;                 // 196608
    float* out_idx = (float*)d_out + 196608;        // 59536 (as float)

    // ---- workspace (float offsets); ~12.3 MiB ----
    float*     ws   = (float*)d_ws;
    float*     zf   = ws;                         // [0 .. 952576)
    float*     e1   = ws + 952576;                // 254016
    float*     e2   = ws + 1206592;               // 492032 (ends 1698624)
    float*     fZq  = ws + 952576;                // decoder phase (ends 1905152)
    float*     fB   = ws + 1905152;               // 492032 (ends 2397184)
    float*     fA   = ws + 2397184;               // 254016 (ends 2651200)
    _Float16*  zh   = (_Float16*)(ws + 2651200);  // 952576 halves
    _Float16*  cbB  = (_Float16*)(ws + 3127488);  // 131072 halves
    float*     cn   = ws + 3193024;               // 8192
    float*     cnT  = ws + 3201216;               // 8192 (= -cn/2, [col][tile])
    unsigned*  scal = (unsigned*)(ws + 3209408);  // 2
    float*     bmax = ws + 3209410;               // 3721

    const int TPB = 256;

    // encoder (fp32, np-order replica)
    conv3x3_np<3, 4, 128, 128, true ><<<993,  TPB, 0, stream>>>(x,  ew1, eb1, e1);
    conv3x3_np<4, 8, 126, 126, true ><<<1922, TPB, 0, stream>>>(e1, ew2, eb2, e2);
    conv3_last_np<<<NCONVBLK, TPB, 0, stream>>>(e2, ew3, eb3, zf, zh, bmax);
    reduce_zmax<<<1, TPB, 0, stream>>>(bmax, scal);   // also inits scal[1]

    // codebook prep + VQ (32x32x16 MFMA, C = -cn/2 folded; 2-pass screen + exact rescore)
    cbprep<<<32, TPB, 0, stream>>>(cb, cn, cnT, cbB, scal);
    vq_mfma<<<NVQBLK, TPB, 0, stream>>>(zh, zf, cbB, cn, cnT, cb, scal, out_idx, fZq);

    // decoder (fp32)
    convt3x3<16, 8, 122, 122, true ><<<1922, TPB, 0, stream>>>(fZq, dw1, db1, fB);
    convt3x3<8, 4, 124, 124, true ><<<993,  TPB, 0, stream>>>(fB,  dw2, db2, fA);
    convt3x3<4, 3, 126, 126, false><<<768,  TPB, 0, stream>>>(fA,  dw3, db3, out_y);
}